// Round 6
// baseline (522.387 us; speedup 1.0000x reference)
//
#include <hip/hip_runtime.h>
#include <hip/hip_bf16.h>

// ConvIntrinsic: gather+barycentric -> patch-operator -> 8 rotated folds.
// Identity: interp[r,a,(rho,alpha)] depends only on (a-alpha)&7, so all 8
// rotations share ONE 256-column B (2.6 MB, L2-resident); the rot-roll is a
// wave-uniform q-permute on A's k-offset. GEMM: virtual M=(rot,slab), N=256,
// K=5120 bf16 MFMA, XCD-swizzled (one sig slab + whole B per XCD L2).
//
// R6: split-K x2 (1536 blocks, the measured-parallelism win) WITHOUT the
// separate epilogue: both slot-blocks write bf16 partials (lane-major,
// coalesced), fence, atomicAdd a per-tile flag; the LAST finisher reads the
// other slot's 32 KB (same-XCD L2 pairing: partner = blockIdx+8), combines
// in-register, applies bias+relu+k-fold, stores out. No spin -> no deadlock.
// Flags zeroed inside prep (no extra dispatch). ws 163 -> 114 MB.

#define N_PTS 6000
#define RR 5
#define AA 8
#define FF 128
#define OO 128
#define QQ 40          // R*A
#define KD 5120        // QQ*FF  (GEMM K)
#define KHALF 2560
#define NCOL 256       // 2 k * 128 o (GEMM N, single-rot B)
#define NTILES 768     // 48 slabs x 8 rot x 2 n0
#define SIG_BLOCKS 1500          // 4 points per block
#define W2_BLOCKS (NCOL / 2)     // 2 j per block

typedef __bf16 bf16_t;
typedef __bf16 bf16x4 __attribute__((ext_vector_type(4)));
typedef __bf16 bf16x8 __attribute__((ext_vector_type(8)));
typedef float f32x4 __attribute__((ext_vector_type(4)));

#define GLOAD_LDS16(g, l)                                              \
  __builtin_amdgcn_global_load_lds(                                    \
      (const __attribute__((address_space(1))) void*)(g),              \
      (__attribute__((address_space(3))) void*)(l), 16, 0, 0)

// ------------------------------------------------------------- prep pass
// blocks [0,1500): sig for 4 points each (bary via LDS, pipelined gathers).
// blocks [1500,1628): Bt (rot=0 only), two j columns per block; block 1500
// also zeroes the GEMM tile flags.
__global__ __launch_bounds__(256) void prep_kernel(
    const float* __restrict__ mesh, const float* __restrict__ bary,
    const float* __restrict__ kw, const float* __restrict__ interp,
    bf16_t* __restrict__ sig, bf16_t* __restrict__ Bt,
    unsigned int* __restrict__ flags) {
  __shared__ float sB[960];           // bary for 4 points (sig branch)
  __shared__ float sI[RR * AA * QQ];  // 1600 floats (w2 branch)
  const int bx = blockIdx.x;
  const int tid = threadIdx.x;

  if (bx < SIG_BLOCKS) {
    const int nb = bx * 4;
    const float4* bsrc = (const float4*)(bary + (size_t)nb * (QQ * 6));
    if (tid < 240) ((float4*)sB)[tid] = bsrc[tid];
    __syncthreads();
    const int qi = tid >> 5;        // 0..7
    const int l = tid & 31;         // f = l*4
    for (int nn = 0; nn < 4; ++nn) {
      bf16_t* sn = sig + (size_t)(nb + nn) * KD;
#pragma unroll
      for (int qb = 0; qb < 5; ++qb) {
        const int q = qb * 8 + qi;
        const float* b = sB + nn * 240 + q * 6;  // broadcast LDS reads
        const int i0 = (int)b[0]; const float w0 = b[1];
        const int i1 = (int)b[2]; const float w1 = b[3];
        const int i2 = (int)b[4]; const float w2 = b[5];
        const float4 v0 = *(const float4*)(mesh + (size_t)i0 * FF + l * 4);
        const float4 v1 = *(const float4*)(mesh + (size_t)i1 * FF + l * 4);
        const float4 v2 = *(const float4*)(mesh + (size_t)i2 * FF + l * 4);
        bf16x4 o;
        o[0] = (bf16_t)(w0 * v0.x + w1 * v1.x + w2 * v2.x);
        o[1] = (bf16_t)(w0 * v0.y + w1 * v1.y + w2 * v2.y);
        o[2] = (bf16_t)(w0 * v0.z + w1 * v1.z + w2 * v2.z);
        o[3] = (bf16_t)(w0 * v0.w + w1 * v1.w + w2 * v2.w);
        *(bf16x4*)(sn + q * FF + l * 4) = o;
      }
    }
  } else {
    if (bx == SIG_BLOCKS)
      for (int i = tid; i < NTILES; i += 256) flags[i] = 0u;
    // ---- w2 (rot=0 only): two j columns per block (128 threads each).
    const int j = (bx - SIG_BLOCKS) * 2 + (tid >> 7);  // 0..255
    const int f = tid & 127;
    for (int i = tid; i < RR * AA * QQ; i += 256) sI[i] = interp[i];
    __syncthreads();
    const int o = (j >> 1) & 127;
    const int k = j & 1;
    float acc[QQ];
#pragma unroll
    for (int q = 0; q < QQ; ++q) acc[q] = 0.f;
    for (int r = 0; r < RR; ++r) {
      for (int a = 0; a < AA; ++a) {
        const float kv =
            kw[((size_t)((r * AA + a) * 2 + k) * OO + o) * FF + f];
        const float4* ip = (const float4*)(sI + (r * AA + a) * QQ);
#pragma unroll
        for (int q4 = 0; q4 < QQ / 4; ++q4) {
          const float4 w4 = ip[q4];
          acc[q4 * 4 + 0] += w4.x * kv;
          acc[q4 * 4 + 1] += w4.y * kv;
          acc[q4 * 4 + 2] += w4.z * kv;
          acc[q4 * 4 + 3] += w4.w * kv;
        }
      }
    }
    bf16_t* bj = Bt + (size_t)j * KD;
#pragma unroll
    for (int q = 0; q < QQ; ++q) bj[q * FF + f] = (bf16_t)acc[q];
  }
}

// ------------------------------------------------- GEMM core (macro body)
// 128x128 tile, BK=64, 4 waves x 4x4 MFMA 16x16x32 bf16, global_load_lds
// width=16, XOR bank swizzle. A k-offset gets the wave-uniform rot-permute:
// q_src = (q & 56) | ((q - rot) & 7)   (BK=64 never straddles a q block).
#define GEMM_CORE(k_lo, k_hi)                                              \
  __shared__ bf16_t As[128 * 64];                                          \
  __shared__ bf16_t Bs[128 * 64];                                          \
  const int tid = threadIdx.x;                                             \
  const int wave = tid >> 6;                                               \
  const int lane = tid & 63;                                               \
  const int quad = lane >> 4;                                              \
  const int tl = lane & 15;                                                \
  const int wm = (wave & 1) * 64;                                          \
  const int wn = (wave >> 1) * 64;                                         \
  const int srow = lane >> 3;                                              \
  const int sc = (lane & 7) ^ srow;                                        \
  f32x4 acc[4][4];                                                         \
  _Pragma("unroll") for (int mm = 0; mm < 4; ++mm)                         \
      _Pragma("unroll") for (int nn = 0; nn < 4; ++nn)                     \
          acc[mm][nn] = {0.f, 0.f, 0.f, 0.f};                              \
  for (int kk = (k_lo); kk < (k_hi); kk += 64) {                           \
    const int qq = kk >> 7;                                                \
    const int akk = (((qq & 56) | ((qq - rot) & 7)) << 7) | (kk & 127);    \
    __syncthreads();                                                       \
    _Pragma("unroll") for (int i = 0; i < 4; ++i) {                        \
      const int row = wave * 32 + i * 8;                                   \
      int gm = m0 + row + srow;                                            \
      gm = gm < N_PTS ? gm : (N_PTS - 1);                                  \
      const int gn = n0 + row + srow;                                      \
      GLOAD_LDS16(Asig + (size_t)gm * KD + akk + sc * 8, As + row * 64);   \
      GLOAD_LDS16(Bt + (size_t)gn * KD + kk + sc * 8, Bs + row * 64);      \
    }                                                                      \
    __syncthreads();                                                       \
    _Pragma("unroll") for (int ks = 0; ks < 2; ++ks) {                     \
      const int ch = (((ks * 4 + quad) ^ (tl & 7)) * 8);                   \
      bf16x8 af[4], bfr[4];                                                \
      _Pragma("unroll") for (int mm = 0; mm < 4; ++mm)                     \
          af[mm] = *(const bf16x8*)(As + (wm + mm * 16 + tl) * 64 + ch);   \
      _Pragma("unroll") for (int nn = 0; nn < 4; ++nn)                     \
          bfr[nn] = *(const bf16x8*)(Bs + (wn + nn * 16 + tl) * 64 + ch);  \
      _Pragma("unroll") for (int mm = 0; mm < 4; ++mm)                     \
          _Pragma("unroll") for (int nn = 0; nn < 4; ++nn)                 \
              acc[mm][nn] = __builtin_amdgcn_mfma_f32_16x16x32_bf16(       \
                  af[mm], bfr[nn], acc[mm][nn], 0, 0, 0);                  \
    }                                                                      \
  }

// -------------------------------- split-K GEMM + last-finisher epilogue
// Grid 1536: xcd=L&7, t=L>>3 (0..191); slot=t&1 (partner at L+8, same xcd
// bit); slab g=xcd+8*(t>>5): 32 inner blocks (2 slot x 8 rot x 2 n0) share
// one 128-row sig slab in one XCD's L2; B (2.6 MB) L2-resident everywhere.
__global__ __launch_bounds__(256) void gemm_split_kernel(
    const bf16_t* __restrict__ Asig, const bf16_t* __restrict__ Bt,
    const float* __restrict__ bias, bf16_t* __restrict__ Cpart,
    unsigned int* __restrict__ flags, float* __restrict__ out) {
  const int L = blockIdx.x;
  const int xcd = L & 7;
  const int t = L >> 3;                // 0..191
  const int g = xcd + 8 * (t >> 5);    // 0..47 sig slab
  const int inner = t & 31;
  const int slot = inner & 1;
  const int rot = (inner >> 1) & 7;
  const int n0b = (inner >> 4) & 1;
  const int n0 = n0b * 128;
  const int m0 = g * 128;
  if (m0 >= N_PTS) return;

  GEMM_CORE(slot * KHALF, (slot + 1) * KHALF)

  const int tile = (g << 4) | (rot << 1) | n0b;
  // ---- write own partial (bf16, lane-major layout; any bijection works
  // since the reader uses the same map). 8 B/lane coalesced stores.
  bf16_t* mine = Cpart + ((size_t)(slot * NTILES + tile) << 14);
#pragma unroll
  for (int mm = 0; mm < 4; ++mm)
#pragma unroll
    for (int nn = 0; nn < 4; ++nn) {
      bf16x4 p;
#pragma unroll
      for (int r = 0; r < 4; ++r) p[r] = (bf16_t)acc[mm][nn][r];
      *(bf16x4*)(mine + ((((wave * 16 + mm * 4 + nn) << 6) + lane) << 2)) = p;
    }
  __threadfence();  // device-scope release of partial stores
  __syncthreads();
  __shared__ unsigned int s_old;
  if (tid == 0) s_old = atomicAdd(&flags[tile], 1u);
  __syncthreads();
  if (s_old == 0) return;  // first finisher: partner will combine

  __threadfence();  // acquire: other slot's partial
  const bf16_t* other = Cpart + ((size_t)((1 - slot) * NTILES + tile) << 14);
#pragma unroll
  for (int mm = 0; mm < 4; ++mm)
#pragma unroll
    for (int nn = 0; nn < 4; ++nn) {
      const bf16x4 p = *(const bf16x4*)(
          other + ((((wave * 16 + mm * 4 + nn) << 6) + lane) << 2));
#pragma unroll
      for (int r = 0; r < 4; ++r) acc[mm][nn][r] += (float)p[r];
    }

  // ---- epilogue: v=relu(acc+40*bias[k,o]); lanes (j, j^1) = (k0,k1) of the
  // same o -> shfl_xor(1) pair-sum; even lanes store out[m, rot*128+o].
#pragma unroll
  for (int nn = 0; nn < 4; ++nn) {
    const int j = n0 + wn + nn * 16 + tl;  // 0..255
    const float bb = 40.0f * bias[((j & 1) << 7) | (j >> 1)];
#pragma unroll
    for (int mm = 0; mm < 4; ++mm) {
      const int mrow = m0 + wm + mm * 16 + quad * 4;
      const f32x4 a = acc[mm][nn];
#pragma unroll
      for (int r = 0; r < 4; ++r) {
        float v = a[r] + bb;
        v = v > 0.f ? v : 0.f;
        const float vs = v + __shfl_xor(v, 1, 64);
        if (((lane & 1) == 0) && (mrow + r < N_PTS))
          out[(size_t)(mrow + r) * 1024 + rot * 128 + (j >> 1)] = vs;
      }
    }
  }
}

// ------------------------------------- fallback: fused single-K GEMM (R5)
__global__ __launch_bounds__(256) void gemm_fused_kernel(
    const bf16_t* __restrict__ Asig, const bf16_t* __restrict__ Bt,
    const float* __restrict__ bias, float* __restrict__ out) {
  const int L = blockIdx.x;
  const int xcd = L & 7;
  const int t = L >> 3;                // 0..95
  const int g = xcd + 8 * (t >> 4);    // 0..47
  const int inner = t & 15;
  const int rot = inner & 7;
  const int n0 = (inner >> 3) * 128;
  const int m0 = g * 128;
  if (m0 >= N_PTS) return;

  GEMM_CORE(0, KD)

#pragma unroll
  for (int nn = 0; nn < 4; ++nn) {
    const int j = n0 + wn + nn * 16 + tl;  // 0..255
    const float bb = 40.0f * bias[((j & 1) << 7) | (j >> 1)];
#pragma unroll
    for (int mm = 0; mm < 4; ++mm) {
      const int mrow = m0 + wm + mm * 16 + quad * 4;
      const f32x4 a = acc[mm][nn];
#pragma unroll
      for (int r = 0; r < 4; ++r) {
        float v = a[r] + bb;
        v = v > 0.f ? v : 0.f;
        const float vs = v + __shfl_xor(v, 1, 64);
        if (((lane & 1) == 0) && (mrow + r < N_PTS))
          out[(size_t)(mrow + r) * 1024 + rot * 128 + (j >> 1)] = vs;
      }
    }
  }
}

extern "C" void kernel_launch(void* const* d_in, const int* in_sizes, int n_in,
                              void* d_out, int out_size, void* d_ws,
                              size_t ws_size, hipStream_t stream) {
  const float* mesh = (const float*)d_in[0];    // (6000,128)
  const float* bary = (const float*)d_in[1];    // (6000,5,8,3,2)
  const float* kw = (const float*)d_in[2];      // (5,8,2,128,128)
  const float* bias = (const float*)d_in[3];    // (2,128)
  const float* interp = (const float*)d_in[4];  // (5,8,40)
  float* out = (float*)d_out;                   // (6000,8,128)

  const size_t sig_bytes = (size_t)N_PTS * KD * 2;           // 61.44 MB
  const size_t bt_bytes = (size_t)NCOL * KD * 2;             // 2.62 MB
  const size_t cp_bytes = (size_t)2 * NTILES * 16384 * 2;    // 50.33 MB
  const size_t fl_bytes = (size_t)NTILES * 4;                // 3 KB

  bf16_t* sig = (bf16_t*)d_ws;
  bf16_t* Bt = (bf16_t*)((char*)d_ws + sig_bytes);
  bf16_t* Cpart = (bf16_t*)((char*)d_ws + sig_bytes + bt_bytes);
  unsigned int* flags =
      (unsigned int*)((char*)d_ws + sig_bytes + bt_bytes + cp_bytes);

  prep_kernel<<<SIG_BLOCKS + W2_BLOCKS, 256, 0, stream>>>(mesh, bary, kw,
                                                          interp, sig, Bt,
                                                          flags);
  if (ws_size >= sig_bytes + bt_bytes + cp_bytes + fl_bytes) {
    gemm_split_kernel<<<1536, 256, 0, stream>>>(sig, Bt, bias, Cpart, flags,
                                                out);
  } else {
    gemm_fused_kernel<<<768, 256, 0, stream>>>(sig, Bt, bias, out);
  }
}

// Round 7
// 255.500 us; speedup vs baseline: 2.0446x; 2.0446x over previous
//
#include <hip/hip_runtime.h>
#include <hip/hip_bf16.h>

// ConvIntrinsic: gather+barycentric -> patch-operator -> 8 rotated folds.
// Identity: interp[r,a,(rho,alpha)] depends only on (a-alpha)&7, so all 8
// rotations share ONE 256-column B (2.6 MB, L2-resident); the rot-roll is a
// wave-uniform q-permute on A's k-offset. GEMM: virtual M=(rot,slab), N=256,
// K=5120 bf16 MFMA, XCD-swizzled (one sig slab + whole B per XCD L2).
//
// R7 = proven parts only. R6's in-kernel combine (device __threadfence per
// block) flushed per-XCD L2 and tripled GEMM time -> reverted. Structure:
//   prep (R5 fat blocks) -> split-K x2 GEMM (R4, 1536 blocks, bf16 partials,
//   lane-major dump) -> tile-combine epilogue (768 blocks, kernel boundary
//   is the sync; no fences anywhere).

#define N_PTS 6000
#define RR 5
#define AA 8
#define FF 128
#define OO 128
#define QQ 40          // R*A
#define KD 5120        // QQ*FF  (GEMM K)
#define KHALF 2560
#define NCOL 256       // 2 k * 128 o (GEMM N, single-rot B)
#define NTILES 768     // 48 slabs x 8 rot x 2 n0
#define SIG_BLOCKS 1500          // 4 points per block
#define W2_BLOCKS (NCOL / 2)     // 2 j per block

typedef __bf16 bf16_t;
typedef __bf16 bf16x4 __attribute__((ext_vector_type(4)));
typedef __bf16 bf16x8 __attribute__((ext_vector_type(8)));
typedef float f32x4 __attribute__((ext_vector_type(4)));

#define GLOAD_LDS16(g, l)                                              \
  __builtin_amdgcn_global_load_lds(                                    \
      (const __attribute__((address_space(1))) void*)(g),              \
      (__attribute__((address_space(3))) void*)(l), 16, 0, 0)

// ------------------------------------------------------------- prep pass
// blocks [0,1500): sig for 4 points each (bary via LDS, pipelined gathers).
// blocks [1500,1628): Bt (rot=0 only), two j columns per block.
__global__ __launch_bounds__(256) void prep_kernel(
    const float* __restrict__ mesh, const float* __restrict__ bary,
    const float* __restrict__ kw, const float* __restrict__ interp,
    bf16_t* __restrict__ sig, bf16_t* __restrict__ Bt) {
  __shared__ float sB[960];           // bary for 4 points (sig branch)
  __shared__ float sI[RR * AA * QQ];  // 1600 floats (w2 branch)
  const int bx = blockIdx.x;
  const int tid = threadIdx.x;

  if (bx < SIG_BLOCKS) {
    const int nb = bx * 4;
    const float4* bsrc = (const float4*)(bary + (size_t)nb * (QQ * 6));
    if (tid < 240) ((float4*)sB)[tid] = bsrc[tid];
    __syncthreads();
    const int qi = tid >> 5;        // 0..7
    const int l = tid & 31;         // f = l*4
    for (int nn = 0; nn < 4; ++nn) {
      bf16_t* sn = sig + (size_t)(nb + nn) * KD;
#pragma unroll
      for (int qb = 0; qb < 5; ++qb) {
        const int q = qb * 8 + qi;
        const float* b = sB + nn * 240 + q * 6;  // broadcast LDS reads
        const int i0 = (int)b[0]; const float w0 = b[1];
        const int i1 = (int)b[2]; const float w1 = b[3];
        const int i2 = (int)b[4]; const float w2 = b[5];
        const float4 v0 = *(const float4*)(mesh + (size_t)i0 * FF + l * 4);
        const float4 v1 = *(const float4*)(mesh + (size_t)i1 * FF + l * 4);
        const float4 v2 = *(const float4*)(mesh + (size_t)i2 * FF + l * 4);
        bf16x4 o;
        o[0] = (bf16_t)(w0 * v0.x + w1 * v1.x + w2 * v2.x);
        o[1] = (bf16_t)(w0 * v0.y + w1 * v1.y + w2 * v2.y);
        o[2] = (bf16_t)(w0 * v0.z + w1 * v1.z + w2 * v2.z);
        o[3] = (bf16_t)(w0 * v0.w + w1 * v1.w + w2 * v2.w);
        *(bf16x4*)(sn + q * FF + l * 4) = o;
      }
    }
  } else {
    // ---- w2 (rot=0 only): two j columns per block (128 threads each).
    const int j = (bx - SIG_BLOCKS) * 2 + (tid >> 7);  // 0..255
    const int f = tid & 127;
    for (int i = tid; i < RR * AA * QQ; i += 256) sI[i] = interp[i];
    __syncthreads();
    const int o = (j >> 1) & 127;
    const int k = j & 1;
    float acc[QQ];
#pragma unroll
    for (int q = 0; q < QQ; ++q) acc[q] = 0.f;
    for (int r = 0; r < RR; ++r) {
      for (int a = 0; a < AA; ++a) {
        const float kv =
            kw[((size_t)((r * AA + a) * 2 + k) * OO + o) * FF + f];
        const float4* ip = (const float4*)(sI + (r * AA + a) * QQ);
#pragma unroll
        for (int q4 = 0; q4 < QQ / 4; ++q4) {
          const float4 w4 = ip[q4];
          acc[q4 * 4 + 0] += w4.x * kv;
          acc[q4 * 4 + 1] += w4.y * kv;
          acc[q4 * 4 + 2] += w4.z * kv;
          acc[q4 * 4 + 3] += w4.w * kv;
        }
      }
    }
    bf16_t* bj = Bt + (size_t)j * KD;
#pragma unroll
    for (int q = 0; q < QQ; ++q) bj[q * FF + f] = (bf16_t)acc[q];
  }
}

// ------------------------------------------------- GEMM core (macro body)
// 128x128 tile, BK=64, 4 waves x 4x4 MFMA 16x16x32 bf16, global_load_lds
// width=16, XOR bank swizzle. A k-offset gets the wave-uniform rot-permute:
// q_src = (q & 56) | ((q - rot) & 7)   (BK=64 never straddles a q block).
#define GEMM_CORE(k_lo, k_hi)                                              \
  __shared__ bf16_t As[128 * 64];                                          \
  __shared__ bf16_t Bs[128 * 64];                                          \
  const int tid = threadIdx.x;                                             \
  const int wave = tid >> 6;                                               \
  const int lane = tid & 63;                                               \
  const int quad = lane >> 4;                                              \
  const int tl = lane & 15;                                                \
  const int wm = (wave & 1) * 64;                                          \
  const int wn = (wave >> 1) * 64;                                         \
  const int srow = lane >> 3;                                              \
  const int sc = (lane & 7) ^ srow;                                        \
  f32x4 acc[4][4];                                                         \
  _Pragma("unroll") for (int mm = 0; mm < 4; ++mm)                         \
      _Pragma("unroll") for (int nn = 0; nn < 4; ++nn)                     \
          acc[mm][nn] = {0.f, 0.f, 0.f, 0.f};                              \
  for (int kk = (k_lo); kk < (k_hi); kk += 64) {                           \
    const int qq = kk >> 7;                                                \
    const int akk = (((qq & 56) | ((qq - rot) & 7)) << 7) | (kk & 127);    \
    __syncthreads();                                                       \
    _Pragma("unroll") for (int i = 0; i < 4; ++i) {                        \
      const int row = wave * 32 + i * 8;                                   \
      int gm = m0 + row + srow;                                            \
      gm = gm < N_PTS ? gm : (N_PTS - 1);                                  \
      const int gn = n0 + row + srow;                                      \
      GLOAD_LDS16(Asig + (size_t)gm * KD + akk + sc * 8, As + row * 64);   \
      GLOAD_LDS16(Bt + (size_t)gn * KD + kk + sc * 8, Bs + row * 64);      \
    }                                                                      \
    __syncthreads();                                                       \
    _Pragma("unroll") for (int ks = 0; ks < 2; ++ks) {                     \
      const int ch = (((ks * 4 + quad) ^ (tl & 7)) * 8);                   \
      bf16x8 af[4], bfr[4];                                                \
      _Pragma("unroll") for (int mm = 0; mm < 4; ++mm)                     \
          af[mm] = *(const bf16x8*)(As + (wm + mm * 16 + tl) * 64 + ch);   \
      _Pragma("unroll") for (int nn = 0; nn < 4; ++nn)                     \
          bfr[nn] = *(const bf16x8*)(Bs + (wn + nn * 16 + tl) * 64 + ch);  \
      _Pragma("unroll") for (int mm = 0; mm < 4; ++mm)                     \
          _Pragma("unroll") for (int nn = 0; nn < 4; ++nn)                 \
              acc[mm][nn] = __builtin_amdgcn_mfma_f32_16x16x32_bf16(       \
                  af[mm], bfr[nn], acc[mm][nn], 0, 0, 0);                  \
    }                                                                      \
  }

// ----------------------------------------------- split-K GEMM (partials)
// Grid 1536: xcd=L&7, t=L>>3 (0..191); slab g=xcd+8*(t>>5): 32 inner blocks
// (2 slot x 8 rot x 2 n0) share one 128-row sig slab in one XCD's L2;
// B (2.6 MB) L2-resident everywhere. Partials: bf16, lane-major fragment
// dump (8 B/lane coalesced; reader uses the same bijection). No fences.
__global__ __launch_bounds__(256) void gemm_split_kernel(
    const bf16_t* __restrict__ Asig, const bf16_t* __restrict__ Bt,
    bf16_t* __restrict__ Cpart) {
  const int L = blockIdx.x;
  const int xcd = L & 7;
  const int t = L >> 3;                // 0..191
  const int g = xcd + 8 * (t >> 5);    // 0..47 sig slab
  const int inner = t & 31;
  const int slot = inner & 1;
  const int rot = (inner >> 1) & 7;
  const int n0b = (inner >> 4) & 1;
  const int n0 = n0b * 128;
  const int m0 = g * 128;
  if (m0 >= N_PTS) return;

  GEMM_CORE(slot * KHALF, (slot + 1) * KHALF)

  const int tile = (g << 4) | (rot << 1) | n0b;
  bf16_t* mine = Cpart + ((size_t)(slot * NTILES + tile) << 14);
#pragma unroll
  for (int mm = 0; mm < 4; ++mm)
#pragma unroll
    for (int nn = 0; nn < 4; ++nn) {
      bf16x4 p;
#pragma unroll
      for (int r = 0; r < 4; ++r) p[r] = (bf16_t)acc[mm][nn][r];
      *(bf16x4*)(mine + ((((wave * 16 + mm * 4 + nn) << 6) + lane) << 2)) = p;
    }
}

// ------------------------- combine epilogue: slot-sum+bias+relu+k-fold
// One block per tile; mirrors the GEMM fragment map. Reads 2 x 32 KB
// coalesced, sums in-register, then the verified epilogue:
// v=relu(acc+40*bias[k,o]); lanes (j, j^1)=(k0,k1) of same o -> shfl_xor(1)
// pair-sum; even lanes store out[m, rot*128+o].
__global__ __launch_bounds__(256) void combine_kernel(
    const bf16_t* __restrict__ Cpart, const float* __restrict__ bias,
    float* __restrict__ out) {
  const int tile = blockIdx.x;
  const int g = tile >> 4;
  const int rot = (tile >> 1) & 7;
  const int n0 = (tile & 1) * 128;
  const int m0 = g * 128;
  if (m0 >= N_PTS) return;
  const int tid = threadIdx.x;
  const int wave = tid >> 6;
  const int lane = tid & 63;
  const int quad = lane >> 4;
  const int tl = lane & 15;
  const int wm = (wave & 1) * 64;
  const int wn = (wave >> 1) * 64;

  const bf16_t* p0 = Cpart + ((size_t)tile << 14);
  const bf16_t* p1 = Cpart + ((size_t)(NTILES + tile) << 14);
  f32x4 acc[4][4];
#pragma unroll
  for (int mm = 0; mm < 4; ++mm)
#pragma unroll
    for (int nn = 0; nn < 4; ++nn) {
      const size_t off = (((wave * 16 + mm * 4 + nn) << 6) + lane) << 2;
      const bf16x4 a = *(const bf16x4*)(p0 + off);
      const bf16x4 b = *(const bf16x4*)(p1 + off);
#pragma unroll
      for (int r = 0; r < 4; ++r) acc[mm][nn][r] = (float)a[r] + (float)b[r];
    }

#pragma unroll
  for (int nn = 0; nn < 4; ++nn) {
    const int j = n0 + wn + nn * 16 + tl;  // 0..255
    const float bb = 40.0f * bias[((j & 1) << 7) | (j >> 1)];
#pragma unroll
    for (int mm = 0; mm < 4; ++mm) {
      const int mrow = m0 + wm + mm * 16 + quad * 4;
      const f32x4 a = acc[mm][nn];
#pragma unroll
      for (int r = 0; r < 4; ++r) {
        float v = a[r] + bb;
        v = v > 0.f ? v : 0.f;
        const float vs = v + __shfl_xor(v, 1, 64);
        if (((lane & 1) == 0) && (mrow + r < N_PTS))
          out[(size_t)(mrow + r) * 1024 + rot * 128 + (j >> 1)] = vs;
      }
    }
  }
}

// ------------------------------------- fallback: fused single-K GEMM (R5)
__global__ __launch_bounds__(256) void gemm_fused_kernel(
    const bf16_t* __restrict__ Asig, const bf16_t* __restrict__ Bt,
    const float* __restrict__ bias, float* __restrict__ out) {
  const int L = blockIdx.x;
  const int xcd = L & 7;
  const int t = L >> 3;                // 0..95
  const int g = xcd + 8 * (t >> 4);    // 0..47
  const int inner = t & 15;
  const int rot = inner & 7;
  const int n0 = (inner >> 3) * 128;
  const int m0 = g * 128;
  if (m0 >= N_PTS) return;

  GEMM_CORE(0, KD)

#pragma unroll
  for (int nn = 0; nn < 4; ++nn) {
    const int j = n0 + wn + nn * 16 + tl;  // 0..255
    const float bb = 40.0f * bias[((j & 1) << 7) | (j >> 1)];
#pragma unroll
    for (int mm = 0; mm < 4; ++mm) {
      const int mrow = m0 + wm + mm * 16 + quad * 4;
      const f32x4 a = acc[mm][nn];
#pragma unroll
      for (int r = 0; r < 4; ++r) {
        float v = a[r] + bb;
        v = v > 0.f ? v : 0.f;
        const float vs = v + __shfl_xor(v, 1, 64);
        if (((lane & 1) == 0) && (mrow + r < N_PTS))
          out[(size_t)(mrow + r) * 1024 + rot * 128 + (j >> 1)] = vs;
      }
    }
  }
}

extern "C" void kernel_launch(void* const* d_in, const int* in_sizes, int n_in,
                              void* d_out, int out_size, void* d_ws,
                              size_t ws_size, hipStream_t stream) {
  const float* mesh = (const float*)d_in[0];    // (6000,128)
  const float* bary = (const float*)d_in[1];    // (6000,5,8,3,2)
  const float* kw = (const float*)d_in[2];      // (5,8,2,128,128)
  const float* bias = (const float*)d_in[3];    // (2,128)
  const float* interp = (const float*)d_in[4];  // (5,8,40)
  float* out = (float*)d_out;                   // (6000,8,128)

  const size_t sig_bytes = (size_t)N_PTS * KD * 2;           // 61.44 MB
  const size_t bt_bytes = (size_t)NCOL * KD * 2;             // 2.62 MB
  const size_t cp_bytes = (size_t)2 * NTILES * 16384 * 2;    // 50.33 MB

  bf16_t* sig = (bf16_t*)d_ws;
  bf16_t* Bt = (bf16_t*)((char*)d_ws + sig_bytes);
  bf16_t* Cpart = (bf16_t*)((char*)d_ws + sig_bytes + bt_bytes);

  prep_kernel<<<SIG_BLOCKS + W2_BLOCKS, 256, 0, stream>>>(mesh, bary, kw,
                                                          interp, sig, Bt);
  if (ws_size >= sig_bytes + bt_bytes + cp_bytes) {
    gemm_split_kernel<<<1536, 256, 0, stream>>>(sig, Bt, Cpart);
    combine_kernel<<<NTILES, 256, 0, stream>>>(Cpart, bias, out);
  } else {
    gemm_fused_kernel<<<768, 256, 0, stream>>>(sig, Bt, bias, out);
  }
}

// Round 8
// 179.291 us; speedup vs baseline: 2.9136x; 1.4251x over previous
//
#include <hip/hip_runtime.h>
#include <hip/hip_bf16.h>

// ConvIntrinsic: gather+barycentric -> patch-operator -> 8 rotated folds.
// R4 identity: C_rot[m,j] = sum_{rho,a} A[m,rho,a]·B[j,rho,(a+rot)&7] — a
// circular CORRELATION over the angular index a (period 8).
// R8: apply the correlation theorem. 8-pt real DFT over a on both sides
// (fused into prep), then ĉ[k] = X*[k]Y[k] as FOUR bf16 GEMMs of
// M=6000, N=512, K=1280 (bins k={0,4},1,2,3; Re/Im packed in K; the 512
// cols produce Re/Im of ĉ) = 31.5 GFLOP vs 126 GFLOP before (4x cut).
// Combine kernel does the 8-pt inverse DFT per (m,j) (coeffs 0,±1,±√2),
// then the verified bias+relu+k-pair-fold epilogue. Partials f32 (bf16 Z
// would add ~0.1-0.25 noise through the x2 iDFT coefficients).
// Split-K x2 -> 1504 blocks (parallelism win from R3/R7 kept); 1/8 DFT
// normalization folded into Bhat.

#define N_PTS 6000
#define RR 5
#define AA 8
#define FF 128
#define OO 128
#define QQ 40            // R*A
#define KD 5120          // legacy GEMM K
#define KD2 1280         // FFT GEMM K: 5 rho x 2 part x 128 f
#define NCOL 256
#define SIG_BLOCKS 1500  // 4 points per block
#define W2_BLOCKS 128    // 2 j per block
#define CCQ 0.70710678118654752f
#define RT2 1.41421356237309515f

#define AHS ((size_t)N_PTS * KD2)  // per-bin Ahat elems
#define BHS ((size_t)512 * KD2)    // per-bin Bhat elems

typedef __bf16 bf16_t;
typedef __bf16 bf16x4 __attribute__((ext_vector_type(4)));
typedef __bf16 bf16x8 __attribute__((ext_vector_type(8)));
typedef float f32x4 __attribute__((ext_vector_type(4)));

#define GLOAD_LDS16(g, l)                                              \
  __builtin_amdgcn_global_load_lds(                                    \
      (const __attribute__((address_space(1))) void*)(g),              \
      (__attribute__((address_space(3))) void*)(l), 16, 0, 0)

// 8-point real DFT, X[k] = sum_a x[a] e^{-2pi i k a/8}; outputs k=0,4 real
// and k=1,2,3 complex (Hermitian half). Verified vs delta impulses.
#define DFT8(x, X0, X4, Xr1, Xi1, Xr2, Xi2, Xr3, Xi3)                  \
  {                                                                    \
    const float s0_ = x[0] + x[4], s1_ = x[1] + x[5];                  \
    const float s2_ = x[2] + x[6], s3_ = x[3] + x[7];                  \
    const float d0_ = x[0] - x[4], d1_ = x[1] - x[5];                  \
    const float d2_ = x[2] - x[6], d3_ = x[3] - x[7];                  \
    const float e_ = CCQ * (d1_ - d3_), o_ = CCQ * (d1_ + d3_);        \
    X0 = (s0_ + s2_) + (s1_ + s3_);                                    \
    X4 = (s0_ + s2_) - (s1_ + s3_);                                    \
    Xr2 = s0_ - s2_; Xi2 = s3_ - s1_;                                  \
    Xr1 = d0_ + e_;  Xi1 = -(o_ + d2_);                                \
    Xr3 = d0_ - e_;  Xi3 = d2_ - o_;                                   \
  }

// ------------------------------------------------------- FFT prep pass
// blocks [0,1500): sig for 4 points -> LDS -> DFT over a -> Ahat[4 bins].
// blocks [1500,1628): Bt columns (rot=0) -> DFT -> Bhat[4 bins] (x 1/8).
__global__ __launch_bounds__(256) void prep_fft_kernel(
    const float* __restrict__ mesh, const float* __restrict__ bary,
    const float* __restrict__ kw, const float* __restrict__ interp,
    bf16_t* __restrict__ Ahat, bf16_t* __restrict__ Bhat) {
  __shared__ float sB[960];             // bary for 4 points
  __shared__ bf16_t sSig[4 * QQ * FF];  // 40 KB sig staging
  __shared__ float sI[RR * AA * QQ];    // 1600 floats (w2 branch)
  const int bx = blockIdx.x;
  const int tid = threadIdx.x;

  if (bx < SIG_BLOCKS) {
    const int nb = bx * 4;
    const float4* bsrc = (const float4*)(bary + (size_t)nb * (QQ * 6));
    if (tid < 240) ((float4*)sB)[tid] = bsrc[tid];
    __syncthreads();
    const int qi = tid >> 5;  // 0..7
    const int l = tid & 31;   // f = l*4
    for (int nn = 0; nn < 4; ++nn) {
#pragma unroll
      for (int qb = 0; qb < 5; ++qb) {
        const int q = qb * 8 + qi;
        const float* b = sB + nn * 240 + q * 6;
        const int i0 = (int)b[0]; const float w0 = b[1];
        const int i1 = (int)b[2]; const float w1 = b[3];
        const int i2 = (int)b[4]; const float w2 = b[5];
        const float4 v0 = *(const float4*)(mesh + (size_t)i0 * FF + l * 4);
        const float4 v1 = *(const float4*)(mesh + (size_t)i1 * FF + l * 4);
        const float4 v2 = *(const float4*)(mesh + (size_t)i2 * FF + l * 4);
        bf16x4 o;
        o[0] = (bf16_t)(w0 * v0.x + w1 * v1.x + w2 * v2.x);
        o[1] = (bf16_t)(w0 * v0.y + w1 * v1.y + w2 * v2.y);
        o[2] = (bf16_t)(w0 * v0.z + w1 * v1.z + w2 * v2.z);
        o[3] = (bf16_t)(w0 * v0.w + w1 * v1.w + w2 * v2.w);
        *(bf16x4*)(sSig + ((nn * QQ + q) << 7) + l * 4) = o;
      }
    }
    __syncthreads();
    // DFT phase: idx = rho*128 + f over 640 slots, 3 passes.
#pragma unroll
    for (int pass = 0; pass < 3; ++pass) {
      const int idx = tid + pass * 256;
      if (idx < 640) {
        const int rho = idx >> 7;
        const int f = idx & 127;
#pragma unroll
        for (int nn = 0; nn < 4; ++nn) {
          float x[8];
#pragma unroll
          for (int a = 0; a < 8; ++a)
            x[a] = (float)sSig[((nn * QQ + rho * 8 + a) << 7) + f];
          float X0, X4, Xr1, Xi1, Xr2, Xi2, Xr3, Xi3;
          DFT8(x, X0, X4, Xr1, Xi1, Xr2, Xi2, Xr3, Xi3);
          bf16_t* dst = Ahat + (size_t)(nb + nn) * KD2 + rho * 256 + f;
          dst[0] = (bf16_t)X0;            dst[128] = (bf16_t)X4;
          dst[AHS] = (bf16_t)Xr1;         dst[AHS + 128] = (bf16_t)Xi1;
          dst[2 * AHS] = (bf16_t)Xr2;     dst[2 * AHS + 128] = (bf16_t)Xi2;
          dst[3 * AHS] = (bf16_t)Xr3;     dst[3 * AHS + 128] = (bf16_t)Xi3;
        }
      }
    }
  } else {
    // ---- B side: two j columns per block (128 threads each).
    const int j = (bx - SIG_BLOCKS) * 2 + (tid >> 7);  // 0..255
    const int f = tid & 127;
    for (int i = tid; i < RR * AA * QQ; i += 256) sI[i] = interp[i];
    __syncthreads();
    const int o = (j >> 1) & 127;
    const int k = j & 1;
    float acc[QQ];
#pragma unroll
    for (int q = 0; q < QQ; ++q) acc[q] = 0.f;
    for (int r = 0; r < RR; ++r) {
      for (int a = 0; a < AA; ++a) {
        const float kv =
            kw[((size_t)((r * AA + a) * 2 + k) * OO + o) * FF + f];
        const float4* ip = (const float4*)(sI + (r * AA + a) * QQ);
#pragma unroll
        for (int q4 = 0; q4 < QQ / 4; ++q4) {
          const float4 w4 = ip[q4];
          acc[q4 * 4 + 0] += w4.x * kv;
          acc[q4 * 4 + 1] += w4.y * kv;
          acc[q4 * 4 + 2] += w4.z * kv;
          acc[q4 * 4 + 3] += w4.w * kv;
        }
      }
    }
    // DFT over a within registers; 1/8 normalization folded in here.
    const float SC = 0.125f;
    bf16_t* b1p = Bhat + (size_t)j * KD2 + f;          // col j (Re-type)
    bf16_t* b2p = Bhat + (size_t)(256 + j) * KD2 + f;  // col 256+j (Im-type)
#pragma unroll
    for (int rho = 0; rho < RR; ++rho) {
      const float* x = acc + rho * 8;
      float Y0, Y4, Yr1, Yi1, Yr2, Yi2, Yr3, Yi3;
      DFT8(x, Y0, Y4, Yr1, Yi1, Yr2, Yi2, Yr3, Yi3);
      const int off = rho * 256;
      // bin04: col j = [Y0|0], col 256+j = [0|Y4]
      b1p[off] = (bf16_t)(Y0 * SC);        b1p[off + 128] = (bf16_t)0.f;
      b2p[off] = (bf16_t)0.f;              b2p[off + 128] = (bf16_t)(Y4 * SC);
      // bin k: col j = [Yr|Yi] (ReZ), col 256+j = [Yi|-Yr] (ImZ)
      b1p[BHS + off] = (bf16_t)(Yr1 * SC);
      b1p[BHS + off + 128] = (bf16_t)(Yi1 * SC);
      b2p[BHS + off] = (bf16_t)(Yi1 * SC);
      b2p[BHS + off + 128] = (bf16_t)(-Yr1 * SC);
      b1p[2 * BHS + off] = (bf16_t)(Yr2 * SC);
      b1p[2 * BHS + off + 128] = (bf16_t)(Yi2 * SC);
      b2p[2 * BHS + off] = (bf16_t)(Yi2 * SC);
      b2p[2 * BHS + off + 128] = (bf16_t)(-Yr2 * SC);
      b1p[3 * BHS + off] = (bf16_t)(Yr3 * SC);
      b1p[3 * BHS + off + 128] = (bf16_t)(Yi3 * SC);
      b2p[3 * BHS + off] = (bf16_t)(Yi3 * SC);
      b2p[3 * BHS + off + 128] = (bf16_t)(-Yr3 * SC);
    }
  }
}

// ----------------------------------------------------------- FFT GEMM
// Per bin (blockIdx.y): C[m,c] = sum_k Ahat[bin][m,k]*Bhat[bin][c,k],
// M=6000, N=512, K=1280, split-K x2. 128x128 tile, BK=64, 4 waves x 4x4
// MFMA 16x16x32 bf16, global_load_lds width=16, XOR bank swizzle (m97
// structure, verified). f32 partial dump, lane-major. Grid x: xcd=i&7,
// t=i>>3: slot=t&1, n0b=(t>>1)&3, g=xcd+8*(t>>3) — same-xcd blocks share
// the A-slab; Bhat[bin] (1.3 MB) L2-resident; bin phases sequential.
__global__ __launch_bounds__(256) void gemm_fft_kernel(
    const bf16_t* __restrict__ Ahat, const bf16_t* __restrict__ Bhat,
    float* __restrict__ Cpart) {
  const int bin = blockIdx.y;
  const int i = blockIdx.x;  // 0..383
  const int xcd = i & 7;
  const int t = i >> 3;      // 0..47
  const int slot = t & 1;
  const int n0b = (t >> 1) & 3;
  const int g = xcd + 8 * (t >> 3);  // 0..47
  const int m0 = g * 128;
  if (m0 >= N_PTS) return;
  const int n0 = n0b * 128;
  const bf16_t* A = Ahat + (size_t)bin * AHS;
  const bf16_t* B = Bhat + (size_t)bin * BHS;

  __shared__ bf16_t As[128 * 64];
  __shared__ bf16_t Bs[128 * 64];
  const int tid = threadIdx.x;
  const int wave = tid >> 6;
  const int lane = tid & 63;
  const int quad = lane >> 4;
  const int tl = lane & 15;
  const int wm = (wave & 1) * 64;
  const int wn = (wave >> 1) * 64;
  const int srow = lane >> 3;
  const int sc = (lane & 7) ^ srow;

  f32x4 acc[4][4];
#pragma unroll
  for (int mm = 0; mm < 4; ++mm)
#pragma unroll
    for (int nn = 0; nn < 4; ++nn) acc[mm][nn] = {0.f, 0.f, 0.f, 0.f};

  const int k_lo = slot * 640;
  for (int kk = k_lo; kk < k_lo + 640; kk += 64) {
    __syncthreads();
#pragma unroll
    for (int i4 = 0; i4 < 4; ++i4) {
      const int row = wave * 32 + i4 * 8;
      int gm = m0 + row + srow;
      gm = gm < N_PTS ? gm : (N_PTS - 1);
      const int gn = n0 + row + srow;
      GLOAD_LDS16(A + (size_t)gm * KD2 + kk + sc * 8, As + row * 64);
      GLOAD_LDS16(B + (size_t)gn * KD2 + kk + sc * 8, Bs + row * 64);
    }
    __syncthreads();
#pragma unroll
    for (int ks = 0; ks < 2; ++ks) {
      const int ch = (((ks * 4 + quad) ^ (tl & 7)) * 8);
      bf16x8 af[4], bfr[4];
#pragma unroll
      for (int mm = 0; mm < 4; ++mm)
        af[mm] = *(const bf16x8*)(As + (wm + mm * 16 + tl) * 64 + ch);
#pragma unroll
      for (int nn = 0; nn < 4; ++nn)
        bfr[nn] = *(const bf16x8*)(Bs + (wn + nn * 16 + tl) * 64 + ch);
#pragma unroll
      for (int mm = 0; mm < 4; ++mm)
#pragma unroll
        for (int nn = 0; nn < 4; ++nn)
          acc[mm][nn] = __builtin_amdgcn_mfma_f32_16x16x32_bf16(
              af[mm], bfr[nn], acc[mm][nn], 0, 0, 0);
    }
  }

  const int tile = ((bin * 48 + g) << 2) | n0b;
  float* mine = Cpart + ((size_t)(slot * 768 + tile) << 14);
#pragma unroll
  for (int mm = 0; mm < 4; ++mm)
#pragma unroll
    for (int nn = 0; nn < 4; ++nn)
      *(f32x4*)(mine + ((((wave * 16 + mm * 4 + nn) << 6) + lane) << 2)) =
          acc[mm][nn];
}

// ----------------------- combine: slot-sum + inverse DFT + bias/relu/fold
// c_rot = Z0' + (-1)^rot Z4' + sum_k [2cos(pi k rot/4) ReZ'_k
//         - 2sin(pi k rot/4) ImZ'_k]   (Z' = Z/8, folded into Bhat).
// Grid 376 = 47 slabs x 2 jt x 4 mm; mirrors the GEMM fragment map.
__global__ __launch_bounds__(256) void combine_fft_kernel(
    const float* __restrict__ Cpart, const float* __restrict__ bias,
    float* __restrict__ out) {
  const int bidx = blockIdx.x;
  const int g = bidx >> 3;      // 0..46
  const int sub = bidx & 7;
  const int jt = sub & 1;
  const int mm = sub >> 1;      // 0..3
  const int m0 = g * 128;
  const int tid = threadIdx.x;
  const int wave = tid >> 6;
  const int lane = tid & 63;
  const int quad = lane >> 4;
  const int tl = lane & 15;
  const int wm = (wave & 1) * 64;
  const int wn = (wave >> 1) * 64;

  static const float SG4[8] = {1, -1, 1, -1, 1, -1, 1, -1};
  static const float C1[8] = {2, RT2, 0, -RT2, -2, -RT2, 0, RT2};
  static const float S1[8] = {0, -RT2, -2, -RT2, 0, RT2, 2, RT2};
  static const float C2[8] = {2, 0, -2, 0, 2, 0, -2, 0};
  static const float S2[8] = {0, -2, 0, 2, 0, -2, 0, 2};
  static const float C3[8] = {2, -RT2, 0, RT2, -2, RT2, 0, -RT2};
  static const float S3[8] = {0, -RT2, 2, -RT2, 0, RT2, -2, RT2};

  const size_t s1o = (size_t)768 << 14;
#pragma unroll
  for (int nn = 0; nn < 4; ++nn) {
    const size_t off =
        (size_t)((((wave * 16 + mm * 4 + nn) << 6) + lane) << 2);
    f32x4 zf[4], zs[4];
#pragma unroll
    for (int b = 0; b < 4; ++b) {
      const size_t tf = ((size_t)(((b * 48 + g) << 2) | jt)) << 14;
      const size_t ts = ((size_t)(((b * 48 + g) << 2) | (2 + jt))) << 14;
      const f32x4 a0 = *(const f32x4*)(Cpart + tf + off);
      const f32x4 a1 = *(const f32x4*)(Cpart + s1o + tf + off);
      const f32x4 b0 = *(const f32x4*)(Cpart + ts + off);
      const f32x4 b1 = *(const f32x4*)(Cpart + s1o + ts + off);
#pragma unroll
      for (int r = 0; r < 4; ++r) {
        zf[b][r] = a0[r] + a1[r];
        zs[b][r] = b0[r] + b1[r];
      }
    }
    const int j = jt * 128 + wn + nn * 16 + tl;  // 0..255
    const float bb = 40.0f * bias[((j & 1) << 7) | (j >> 1)];
#pragma unroll
    for (int r = 0; r < 4; ++r) {
      const int mrow = m0 + wm + mm * 16 + quad * 4 + r;
      const float z0 = zf[0][r], z4 = zs[0][r];
      const float r1 = zf[1][r], i1 = zs[1][r];
      const float r2 = zf[2][r], i2 = zs[2][r];
      const float r3 = zf[3][r], i3 = zs[3][r];
      const bool wr = ((lane & 1) == 0) && (mrow < N_PTS);
      float* op = out + (size_t)mrow * 1024 + (j >> 1);
#pragma unroll
      for (int rot = 0; rot < 8; ++rot) {
        const float c = z0 + SG4[rot] * z4 + C1[rot] * r1 + S1[rot] * i1 +
                        C2[rot] * r2 + S2[rot] * i2 + C3[rot] * r3 +
                        S3[rot] * i3;
        float v = c + bb;
        v = v > 0.f ? v : 0.f;
        const float vs = v + __shfl_xor(v, 1, 64);
        if (wr) op[rot * 128] = vs;
      }
    }
  }
}

// ===================== legacy fallback (R7 path, ws-size insurance) ======
__global__ __launch_bounds__(256) void prep_legacy_kernel(
    const float* __restrict__ mesh, const float* __restrict__ bary,
    const float* __restrict__ kw, const float* __restrict__ interp,
    bf16_t* __restrict__ sig, bf16_t* __restrict__ Bt) {
  __shared__ float sB[960];
  __shared__ float sI[RR * AA * QQ];
  const int bx = blockIdx.x;
  const int tid = threadIdx.x;
  if (bx < SIG_BLOCKS) {
    const int nb = bx * 4;
    const float4* bsrc = (const float4*)(bary + (size_t)nb * (QQ * 6));
    if (tid < 240) ((float4*)sB)[tid] = bsrc[tid];
    __syncthreads();
    const int qi = tid >> 5;
    const int l = tid & 31;
    for (int nn = 0; nn < 4; ++nn) {
      bf16_t* sn = sig + (size_t)(nb + nn) * KD;
#pragma unroll
      for (int qb = 0; qb < 5; ++qb) {
        const int q = qb * 8 + qi;
        const float* b = sB + nn * 240 + q * 6;
        const int i0 = (int)b[0]; const float w0 = b[1];
        const int i1 = (int)b[2]; const float w1 = b[3];
        const int i2 = (int)b[4]; const float w2 = b[5];
        const float4 v0 = *(const float4*)(mesh + (size_t)i0 * FF + l * 4);
        const float4 v1 = *(const float4*)(mesh + (size_t)i1 * FF + l * 4);
        const float4 v2 = *(const float4*)(mesh + (size_t)i2 * FF + l * 4);
        bf16x4 o;
        o[0] = (bf16_t)(w0 * v0.x + w1 * v1.x + w2 * v2.x);
        o[1] = (bf16_t)(w0 * v0.y + w1 * v1.y + w2 * v2.y);
        o[2] = (bf16_t)(w0 * v0.z + w1 * v1.z + w2 * v2.z);
        o[3] = (bf16_t)(w0 * v0.w + w1 * v1.w + w2 * v2.w);
        *(bf16x4*)(sn + q * FF + l * 4) = o;
      }
    }
  } else {
    const int j = (bx - SIG_BLOCKS) * 2 + (tid >> 7);
    const int f = tid & 127;
    for (int i = tid; i < RR * AA * QQ; i += 256) sI[i] = interp[i];
    __syncthreads();
    const int o = (j >> 1) & 127;
    const int k = j & 1;
    float acc[QQ];
#pragma unroll
    for (int q = 0; q < QQ; ++q) acc[q] = 0.f;
    for (int r = 0; r < RR; ++r)
      for (int a = 0; a < AA; ++a) {
        const float kv =
            kw[((size_t)((r * AA + a) * 2 + k) * OO + o) * FF + f];
        const float4* ip = (const float4*)(sI + (r * AA + a) * QQ);
#pragma unroll
        for (int q4 = 0; q4 < QQ / 4; ++q4) {
          const float4 w4 = ip[q4];
          acc[q4 * 4 + 0] += w4.x * kv;
          acc[q4 * 4 + 1] += w4.y * kv;
          acc[q4 * 4 + 2] += w4.z * kv;
          acc[q4 * 4 + 3] += w4.w * kv;
        }
      }
    bf16_t* bj = Bt + (size_t)j * KD;
#pragma unroll
    for (int q = 0; q < QQ; ++q) bj[q * FF + f] = (bf16_t)acc[q];
  }
}

__global__ __launch_bounds__(256) void gemm_fused_kernel(
    const bf16_t* __restrict__ Asig, const bf16_t* __restrict__ Bt,
    const float* __restrict__ bias, float* __restrict__ out) {
  const int L = blockIdx.x;
  const int xcd = L & 7;
  const int t = L >> 3;
  const int g = xcd + 8 * (t >> 4);
  const int inner = t & 15;
  const int rot = inner & 7;
  const int n0 = (inner >> 3) * 128;
  const int m0 = g * 128;
  if (m0 >= N_PTS) return;

  __shared__ bf16_t As[128 * 64];
  __shared__ bf16_t Bs[128 * 64];
  const int tid = threadIdx.x;
  const int wave = tid >> 6;
  const int lane = tid & 63;
  const int quad = lane >> 4;
  const int tl = lane & 15;
  const int wm = (wave & 1) * 64;
  const int wn = (wave >> 1) * 64;
  const int srow = lane >> 3;
  const int sc = (lane & 7) ^ srow;
  f32x4 acc[4][4];
#pragma unroll
  for (int mm = 0; mm < 4; ++mm)
#pragma unroll
    for (int nn = 0; nn < 4; ++nn) acc[mm][nn] = {0.f, 0.f, 0.f, 0.f};
  for (int kk = 0; kk < KD; kk += 64) {
    const int qq = kk >> 7;
    const int akk = (((qq & 56) | ((qq - rot) & 7)) << 7) | (kk & 127);
    __syncthreads();
#pragma unroll
    for (int i4 = 0; i4 < 4; ++i4) {
      const int row = wave * 32 + i4 * 8;
      int gm = m0 + row + srow;
      gm = gm < N_PTS ? gm : (N_PTS - 1);
      const int gn = n0 + row + srow;
      GLOAD_LDS16(Asig + (size_t)gm * KD + akk + sc * 8, As + row * 64);
      GLOAD_LDS16(Bt + (size_t)gn * KD + kk + sc * 8, Bs + row * 64);
    }
    __syncthreads();
#pragma unroll
    for (int ks = 0; ks < 2; ++ks) {
      const int ch = (((ks * 4 + quad) ^ (tl & 7)) * 8);
      bf16x8 af[4], bfr[4];
#pragma unroll
      for (int mm = 0; mm < 4; ++mm)
        af[mm] = *(const bf16x8*)(As + (wm + mm * 16 + tl) * 64 + ch);
#pragma unroll
      for (int nn = 0; nn < 4; ++nn)
        bfr[nn] = *(const bf16x8*)(Bs + (wn + nn * 16 + tl) * 64 + ch);
#pragma unroll
      for (int mm = 0; mm < 4; ++mm)
#pragma unroll
        for (int nn = 0; nn < 4; ++nn)
          acc[mm][nn] = __builtin_amdgcn_mfma_f32_16x16x32_bf16(
              af[mm], bfr[nn], acc[mm][nn], 0, 0, 0);
    }
  }
#pragma unroll
  for (int nn = 0; nn < 4; ++nn) {
    const int j = n0 + wn + nn * 16 + tl;
    const float bb = 40.0f * bias[((j & 1) << 7) | (j >> 1)];
#pragma unroll
    for (int mm = 0; mm < 4; ++mm) {
      const int mrow = m0 + wm + mm * 16 + quad * 4;
      const f32x4 a = acc[mm][nn];
#pragma unroll
      for (int r = 0; r < 4; ++r) {
        float v = a[r] + bb;
        v = v > 0.f ? v : 0.f;
        const float vs = v + __shfl_xor(v, 1, 64);
        if (((lane & 1) == 0) && (mrow + r < N_PTS))
          out[(size_t)(mrow + r) * 1024 + rot * 128 + (j >> 1)] = vs;
      }
    }
  }
}

extern "C" void kernel_launch(void* const* d_in, const int* in_sizes, int n_in,
                              void* d_out, int out_size, void* d_ws,
                              size_t ws_size, hipStream_t stream) {
  const float* mesh = (const float*)d_in[0];    // (6000,128)
  const float* bary = (const float*)d_in[1];    // (6000,5,8,3,2)
  const float* kw = (const float*)d_in[2];      // (5,8,2,128,128)
  const float* bias = (const float*)d_in[3];    // (2,128)
  const float* interp = (const float*)d_in[4];  // (5,8,40)
  float* out = (float*)d_out;                   // (6000,8,128)

  const size_t ahat_bytes = 4 * AHS * 2;                  // 61.44 MB
  const size_t bhat_bytes = 4 * BHS * 2;                  // 5.24 MB
  const size_t cp_bytes = (size_t)2 * 768 * 16384 * 4;    // 100.66 MB

  if (ws_size >= ahat_bytes + bhat_bytes + cp_bytes) {
    bf16_t* Ahat = (bf16_t*)d_ws;
    bf16_t* Bhat = (bf16_t*)((char*)d_ws + ahat_bytes);
    float* Cpart = (float*)((char*)d_ws + ahat_bytes + bhat_bytes);
    prep_fft_kernel<<<SIG_BLOCKS + W2_BLOCKS, 256, 0, stream>>>(
        mesh, bary, kw, interp, Ahat, Bhat);
    gemm_fft_kernel<<<dim3(384, 4), 256, 0, stream>>>(Ahat, Bhat, Cpart);
    combine_fft_kernel<<<376, 256, 0, stream>>>(Cpart, bias, out);
  } else {
    bf16_t* sig = (bf16_t*)d_ws;
    bf16_t* Bt = (bf16_t*)((char*)d_ws + (size_t)N_PTS * KD * 2);
    prep_legacy_kernel<<<SIG_BLOCKS + W2_BLOCKS, 256, 0, stream>>>(
        mesh, bary, kw, interp, sig, Bt);
    gemm_fused_kernel<<<768, 256, 0, stream>>>(sig, Bt, bias, out);
  }
}

// Round 9
// 162.976 us; speedup vs baseline: 3.2053x; 1.1001x over previous
//
#include <hip/hip_runtime.h>
#include <hip/hip_bf16.h>

// ConvIntrinsic: gather+barycentric -> patch-operator -> 8 rotated folds.
// Circular-correlation FFT formulation (R8, verified): 8-pt real DFT over
// the angular index on both sides; ĉ[k]=X*[k]Y[k] per bin k={0&4,1,2,3};
// inverse DFT + bias + relu + k-pair fold give the 8 rotation outputs.
//
// R9: FULLY FUSED. One GEMM kernel owns all 4 bins of a (128m x 16j) tile:
// bins loop sequentially (K=4x1280 -> 80 BK iters), the C-fragment holds
// Re Z (col j) and Im Z (col 256+j) in the SAME lane, so the per-bin iDFT
// fold is 2 FMAs into an 8-rot register accumulator (64 VGPRs). No Cpart,
// no combine kernel (R8's 100 MB write + 100 MB read + 3rd dispatch gone).
// Prep sig branch register-direct: gather -> DFT8 in regs -> bf16x4 stores
// (R8's LDS round trip + scalar ds_read_u16/2B-stores eliminated).

#define N_PTS 6000
#define RR 5
#define AA 8
#define FF 128
#define OO 128
#define QQ 40            // R*A
#define KD2 1280         // per-bin GEMM K: 5 rho x 2 part x 128 f
#define SIG_BLOCKS 750   // 8 points per block
#define W2_BLOCKS 128    // 2 j per block
#define CCQ 0.70710678118654752f
#define RT2 1.41421356237309515f

#define AHS ((size_t)N_PTS * KD2)  // per-bin Ahat elems
#define BHS ((size_t)512 * KD2)    // per-bin Bhat elems

typedef __bf16 bf16_t;
typedef __bf16 bf16x4 __attribute__((ext_vector_type(4)));
typedef __bf16 bf16x8 __attribute__((ext_vector_type(8)));
typedef float f32x4 __attribute__((ext_vector_type(4)));

#define GLOAD_LDS16(g, l)                                              \
  __builtin_amdgcn_global_load_lds(                                    \
      (const __attribute__((address_space(1))) void*)(g),              \
      (__attribute__((address_space(3))) void*)(l), 16, 0, 0)

// 8-point real DFT, X[k] = sum_a x[a] e^{-2pi i k a/8} (verified R8).
#define DFT8V(xx, c, X0, X4, Xr1, Xi1, Xr2, Xi2, Xr3, Xi3)             \
  {                                                                    \
    const float s0_ = xx[0][c] + xx[4][c], s1_ = xx[1][c] + xx[5][c];  \
    const float s2_ = xx[2][c] + xx[6][c], s3_ = xx[3][c] + xx[7][c];  \
    const float d0_ = xx[0][c] - xx[4][c], d1_ = xx[1][c] - xx[5][c];  \
    const float d2_ = xx[2][c] - xx[6][c], d3_ = xx[3][c] - xx[7][c];  \
    const float e_ = CCQ * (d1_ - d3_), o_ = CCQ * (d1_ + d3_);        \
    X0 = (s0_ + s2_) + (s1_ + s3_);                                    \
    X4 = (s0_ + s2_) - (s1_ + s3_);                                    \
    Xr2 = s0_ - s2_; Xi2 = s3_ - s1_;                                  \
    Xr1 = d0_ + e_;  Xi1 = -(o_ + d2_);                                \
    Xr3 = d0_ - e_;  Xi3 = d2_ - o_;                                   \
  }

#define PACK4(dst, X)                                                  \
  {                                                                    \
    bf16x4 pv_;                                                        \
    pv_[0] = (bf16_t)X[0]; pv_[1] = (bf16_t)X[1];                      \
    pv_[2] = (bf16_t)X[2]; pv_[3] = (bf16_t)X[3];                      \
    *(bf16x4*)(dst) = pv_;                                             \
  }

// ------------------------------------------------------- FFT prep pass
// blocks [0,750): 8 points each; 256 thr = 8 point-slots x 32 f4-lanes.
//   Register-direct: gather 24 float4 per (point,rho), DFT8 per f-comp,
//   8 packed bf16x4 stores into the 4 bins. No LDS, no barriers.
// blocks [750,878): Bhat (rot=0 cols) -> DFT -> 4 bins (x 1/8 norm).
__global__ __launch_bounds__(256) void prep_fft_kernel(
    const float* __restrict__ mesh, const float* __restrict__ bary,
    const float* __restrict__ kw, const float* __restrict__ interp,
    bf16_t* __restrict__ Ahat, bf16_t* __restrict__ Bhat) {
  __shared__ float sI[RR * AA * QQ];  // w2 branch only
  const int bx = blockIdx.x;
  const int tid = threadIdx.x;

  if (bx < SIG_BLOCKS) {
    const int slot = tid >> 5;  // 0..7
    const int l = tid & 31;     // f = l*4
    const int n = bx * 8 + slot;
    const float* bn = bary + (size_t)n * (QQ * 6);
    bf16_t* an = Ahat + (size_t)n * KD2 + l * 4;
#pragma unroll
    for (int rho = 0; rho < RR; ++rho) {
      float x[8][4];
#pragma unroll
      for (int a = 0; a < 8; ++a) {
        const float* b = bn + (rho * 8 + a) * 6;  // uniform in 32-lane group
        const float2 p0 = *(const float2*)(b);
        const float2 p1 = *(const float2*)(b + 2);
        const float2 p2 = *(const float2*)(b + 4);
        const float4 v0 =
            *(const float4*)(mesh + (size_t)((int)p0.x) * FF + l * 4);
        const float4 v1 =
            *(const float4*)(mesh + (size_t)((int)p1.x) * FF + l * 4);
        const float4 v2 =
            *(const float4*)(mesh + (size_t)((int)p2.x) * FF + l * 4);
        x[a][0] = p0.y * v0.x + p1.y * v1.x + p2.y * v2.x;
        x[a][1] = p0.y * v0.y + p1.y * v1.y + p2.y * v2.y;
        x[a][2] = p0.y * v0.z + p1.y * v1.z + p2.y * v2.z;
        x[a][3] = p0.y * v0.w + p1.y * v1.w + p2.y * v2.w;
      }
      float X0[4], X4[4], Xr1[4], Xi1[4], Xr2[4], Xi2[4], Xr3[4], Xi3[4];
#pragma unroll
      for (int c = 0; c < 4; ++c)
        DFT8V(x, c, X0[c], X4[c], Xr1[c], Xi1[c], Xr2[c], Xi2[c], Xr3[c],
              Xi3[c]);
      bf16_t* dst = an + rho * 256;
      PACK4(dst, X0);                  PACK4(dst + 128, X4);
      PACK4(dst + AHS, Xr1);           PACK4(dst + AHS + 128, Xi1);
      PACK4(dst + 2 * AHS, Xr2);       PACK4(dst + 2 * AHS + 128, Xi2);
      PACK4(dst + 3 * AHS, Xr3);       PACK4(dst + 3 * AHS + 128, Xi3);
    }
  } else {
    // ---- B side: two j columns per block (128 threads each).
    const int j = (bx - SIG_BLOCKS) * 2 + (tid >> 7);  // 0..255
    const int f = tid & 127;
    for (int i = tid; i < RR * AA * QQ; i += 256) sI[i] = interp[i];
    __syncthreads();
    const int o = (j >> 1) & 127;
    const int k = j & 1;
    float acc[QQ];
#pragma unroll
    for (int q = 0; q < QQ; ++q) acc[q] = 0.f;
    for (int r = 0; r < RR; ++r) {
      for (int a = 0; a < AA; ++a) {
        const float kv =
            kw[((size_t)((r * AA + a) * 2 + k) * OO + o) * FF + f];
        const float4* ip = (const float4*)(sI + (r * AA + a) * QQ);
#pragma unroll
        for (int q4 = 0; q4 < QQ / 4; ++q4) {
          const float4 w4 = ip[q4];
          acc[q4 * 4 + 0] += w4.x * kv;
          acc[q4 * 4 + 1] += w4.y * kv;
          acc[q4 * 4 + 2] += w4.z * kv;
          acc[q4 * 4 + 3] += w4.w * kv;
        }
      }
    }
    // DFT over a; 1/8 normalization folded in. Col j = Re-type, 256+j =
    // Im-type (bin0 packs Z0/Z4 there; bins 1-3 pack [Yr|Yi]/[Yi|-Yr]).
    const float SC = 0.125f;
    bf16_t* b1p = Bhat + (size_t)j * KD2 + f;
    bf16_t* b2p = Bhat + (size_t)(256 + j) * KD2 + f;
#pragma unroll
    for (int rho = 0; rho < RR; ++rho) {
      float xx[8][1];
#pragma unroll
      for (int a = 0; a < 8; ++a) xx[a][0] = acc[rho * 8 + a];
      float Y0, Y4, Yr1, Yi1, Yr2, Yi2, Yr3, Yi3;
      DFT8V(xx, 0, Y0, Y4, Yr1, Yi1, Yr2, Yi2, Yr3, Yi3);
      const int off = rho * 256;
      b1p[off] = (bf16_t)(Y0 * SC);        b1p[off + 128] = (bf16_t)0.f;
      b2p[off] = (bf16_t)0.f;              b2p[off + 128] = (bf16_t)(Y4 * SC);
      b1p[BHS + off] = (bf16_t)(Yr1 * SC);
      b1p[BHS + off + 128] = (bf16_t)(Yi1 * SC);
      b2p[BHS + off] = (bf16_t)(Yi1 * SC);
      b2p[BHS + off + 128] = (bf16_t)(-Yr1 * SC);
      b1p[2 * BHS + off] = (bf16_t)(Yr2 * SC);
      b1p[2 * BHS + off + 128] = (bf16_t)(Yi2 * SC);
      b2p[2 * BHS + off] = (bf16_t)(Yi2 * SC);
      b2p[2 * BHS + off + 128] = (bf16_t)(-Yr2 * SC);
      b1p[3 * BHS + off] = (bf16_t)(Yr3 * SC);
      b1p[3 * BHS + off + 128] = (bf16_t)(Yi3 * SC);
      b2p[3 * BHS + off] = (bf16_t)(Yi3 * SC);
      b2p[3 * BHS + off + 128] = (bf16_t)(-Yr3 * SC);
    }
  }
}

// --------------------------------------- fused GEMM + iDFT + epilogue
// Grid 768: xcd=L&7, t=L>>3; slab g=xcd+8*(t>>4) (0..47), j-tile jt=t&15.
// Block = 128m x 16j; B tile = 32 cols (rows 0-15: cols j0+., Re Z; rows
// 16-31: cols 256+j0+., Im Z) -> same lane holds Re/Im of the same j.
// Bins loop sequentially (K=80 BK-iters total); after each bin's K-loop,
// fold cf*Re+sf*Im into an 8-rot accumulator (iDFT coeffs, verified R8).
// Then bias+relu+shfl k-fold epilogue (verified R1-R8).
__global__ __launch_bounds__(256, 3) void gemm_fused_fft_kernel(
    const bf16_t* __restrict__ Ahat, const bf16_t* __restrict__ Bhat,
    const float* __restrict__ bias, float* __restrict__ out) {
  const int L = blockIdx.x;
  const int xcd = L & 7;
  const int t = L >> 3;                // 0..95
  const int g = xcd + 8 * (t >> 4);    // 0..47
  const int jt = t & 15;
  const int m0 = g * 128;
  if (m0 >= N_PTS) return;
  const int j0 = jt * 16;

  __shared__ bf16_t As[128 * 64];
  __shared__ bf16_t Bs[32 * 64];
  const int tid = threadIdx.x;
  const int wave = tid >> 6;
  const int lane = tid & 63;
  const int quad = lane >> 4;
  const int tl = lane & 15;
  const int wm = wave * 32;
  const int srow = lane >> 3;
  const int sc = (lane & 7) ^ srow;

  // this wave's B staging chunk (8 rows of the 32-row B tile)
  const int crow = wave * 8;
  const int colbase = (crow < 16) ? (j0 + crow) : (256 + j0 + (crow - 16));
  const int gcol = colbase + srow;

  // iDFT coefficients: c_rot = sum_b cf[b][rot]*ReZ_b + sf[b][rot]*ImZ_b
  // (bin0: ReZ=Z0 cf=1, ImZ=Z4 sf=(-1)^rot). Verified in R8.
  static const float CF[4][8] = {
      {1, 1, 1, 1, 1, 1, 1, 1},
      {2, RT2, 0, -RT2, -2, -RT2, 0, RT2},
      {2, 0, -2, 0, 2, 0, -2, 0},
      {2, -RT2, 0, RT2, -2, RT2, 0, -RT2}};
  static const float SF[4][8] = {
      {1, -1, 1, -1, 1, -1, 1, -1},
      {0, -RT2, -2, -RT2, 0, RT2, 2, RT2},
      {0, -2, 0, 2, 0, -2, 0, 2},
      {0, -RT2, 2, -RT2, 0, RT2, -2, RT2}};

  f32x4 oacc[8][2];
#pragma unroll
  for (int rot = 0; rot < 8; ++rot)
#pragma unroll
    for (int mm = 0; mm < 2; ++mm) oacc[rot][mm] = {0.f, 0.f, 0.f, 0.f};

#pragma unroll
  for (int b = 0; b < 4; ++b) {
    const bf16_t* A = Ahat + (size_t)b * AHS;
    const bf16_t* B = Bhat + (size_t)b * BHS;
    f32x4 z[2][2];
#pragma unroll
    for (int mm = 0; mm < 2; ++mm)
#pragma unroll
      for (int cc = 0; cc < 2; ++cc) z[mm][cc] = {0.f, 0.f, 0.f, 0.f};

    for (int kk = 0; kk < KD2; kk += 64) {
      __syncthreads();
#pragma unroll
      for (int i = 0; i < 4; ++i) {
        const int row = wave * 32 + i * 8;
        int gm = m0 + row + srow;
        gm = gm < N_PTS ? gm : (N_PTS - 1);
        GLOAD_LDS16(A + (size_t)gm * KD2 + kk + sc * 8, As + row * 64);
      }
      GLOAD_LDS16(B + (size_t)gcol * KD2 + kk + sc * 8, Bs + crow * 64);
      __syncthreads();
#pragma unroll
      for (int ks = 0; ks < 2; ++ks) {
        const int ch = (((ks * 4 + quad) ^ (tl & 7)) * 8);
        bf16x8 af[2], bfr[2];
        af[0] = *(const bf16x8*)(As + (wm + tl) * 64 + ch);
        af[1] = *(const bf16x8*)(As + (wm + 16 + tl) * 64 + ch);
        bfr[0] = *(const bf16x8*)(Bs + tl * 64 + ch);
        bfr[1] = *(const bf16x8*)(Bs + (16 + tl) * 64 + ch);
#pragma unroll
        for (int mm = 0; mm < 2; ++mm)
#pragma unroll
          for (int cc = 0; cc < 2; ++cc)
            z[mm][cc] = __builtin_amdgcn_mfma_f32_16x16x32_bf16(
                af[mm], bfr[cc], z[mm][cc], 0, 0, 0);
      }
    }
    // fold this bin into the 8-rot accumulator
#pragma unroll
    for (int rot = 0; rot < 8; ++rot) {
      const float cf = CF[b][rot], sf = SF[b][rot];
#pragma unroll
      for (int mm = 0; mm < 2; ++mm)
#pragma unroll
        for (int r = 0; r < 4; ++r)
          oacc[rot][mm][r] += cf * z[mm][0][r] + sf * z[mm][1][r];
    }
  }

  // epilogue: v=relu(oacc+40*bias[k,o]); lanes (tl, tl^1)=(k0,k1) of same o
  const int j = j0 + tl;  // 0..255
  const float bb = 40.0f * bias[((j & 1) << 7) | (j >> 1)];
  const int o = j >> 1;
#pragma unroll
  for (int rot = 0; rot < 8; ++rot)
#pragma unroll
    for (int mm = 0; mm < 2; ++mm)
#pragma unroll
      for (int r = 0; r < 4; ++r) {
        const int mrow = m0 + wm + mm * 16 + quad * 4 + r;
        float v = oacc[rot][mm][r] + bb;
        v = v > 0.f ? v : 0.f;
        const float vs = v + __shfl_xor(v, 1, 64);
        if (((lane & 1) == 0) && (mrow < N_PTS))
          out[(size_t)mrow * 1024 + rot * 128 + o] = vs;
      }
}

extern "C" void kernel_launch(void* const* d_in, const int* in_sizes, int n_in,
                              void* d_out, int out_size, void* d_ws,
                              size_t ws_size, hipStream_t stream) {
  const float* mesh = (const float*)d_in[0];    // (6000,128)
  const float* bary = (const float*)d_in[1];    // (6000,5,8,3,2)
  const float* kw = (const float*)d_in[2];      // (5,8,2,128,128)
  const float* bias = (const float*)d_in[3];    // (2,128)
  const float* interp = (const float*)d_in[4];  // (5,8,40)
  float* out = (float*)d_out;                   // (6000,8,128)

  bf16_t* Ahat = (bf16_t*)d_ws;                          // 61.44 MB
  bf16_t* Bhat = (bf16_t*)((char*)d_ws + 4 * AHS * 2);   // +5.24 MB

  prep_fft_kernel<<<SIG_BLOCKS + W2_BLOCKS, 256, 0, stream>>>(
      mesh, bary, kw, interp, Ahat, Bhat);
  gemm_fused_fft_kernel<<<768, 256, 0, stream>>>(Ahat, Bhat, bias, out);
}